// Round 3
// baseline (385.073 us; speedup 1.0000x reference)
//
#include <hip/hip_runtime.h>

// Problem constants (all fp32 in global memory — verified round 2)
#define BS    8
#define CDIM  4096
#define TDIM  512
#define NH    8
#define HD    64
#define NDIM  512
#define INV_SCALE 0.044194173824159216f   // 1/sqrt(512)

typedef __bf16 bf16x8 __attribute__((ext_vector_type(8)));
typedef float  f32x4  __attribute__((ext_vector_type(4)));

static __device__ __forceinline__ unsigned short f2b(float f) {
    union { float f; unsigned int i; } x; x.f = f;
    unsigned int r = x.i + 0x7FFFu + ((x.i >> 16) & 1u);   // RNE
    return (unsigned short)(r >> 16);
}

static __device__ __forceinline__ void gl2lds16(const unsigned short* g,
                                                unsigned short* l) {
    __builtin_amdgcn_global_load_lds(
        (const __attribute__((address_space(1))) void*)g,
        (__attribute__((address_space(3))) void*)l, 16, 0, 0);
}

// ---------------------------------------------------------------------------
// Transpose+convert: x[b][c][t] fp32 -> xT[b][t][c] bf16.  64x64 tiles.
// ---------------------------------------------------------------------------
__global__ __launch_bounds__(256) void transpose_qk_kernel(
    const float* __restrict__ q, const float* __restrict__ k,
    unsigned short* __restrict__ qT, unsigned short* __restrict__ kT)
{
    __shared__ unsigned short Ls[64 * 65];

    const int z = blockIdx.z;
    const int b = z & 7;
    const float* src = (z >> 3) ? k : q;
    unsigned short* dst = (z >> 3) ? kT : qT;

    const int c0 = blockIdx.x * 64;
    const int t0 = blockIdx.y * 64;
    const int tid = threadIdx.x;

    {
        const int r = tid >> 2, seg = (tid & 3) * 16;
        const float* p = src + ((size_t)b * CDIM + c0 + r) * TDIM + t0 + seg;
        float4 f0 = *(const float4*)p, f1 = *(const float4*)(p + 4);
        float4 f2 = *(const float4*)(p + 8), f3 = *(const float4*)(p + 12);
        float ff[16] = {f0.x, f0.y, f0.z, f0.w, f1.x, f1.y, f1.z, f1.w,
                        f2.x, f2.y, f2.z, f2.w, f3.x, f3.y, f3.z, f3.w};
#pragma unroll
        for (int j = 0; j < 16; j++) Ls[(seg + j) * 65 + r] = f2b(ff[j]);
    }
    __syncthreads();
    {
        const int tp = tid >> 2, cs = (tid & 3) * 16;
        alignas(16) unsigned short u[16];
#pragma unroll
        for (int j = 0; j < 16; j++) u[j] = Ls[tp * 65 + cs + j];
        unsigned short* o = dst + ((size_t)b * TDIM + t0 + tp) * CDIM + c0 + cs;
        *(float4*)o = *(const float4*)u;
        *(float4*)(o + 8) = *(const float4*)(u + 8);
    }
}

// ---------------------------------------------------------------------------
// Elementwise fp32 -> bf16 (n8 = n/8; one thread = 8 elems)
// ---------------------------------------------------------------------------
__global__ __launch_bounds__(256) void cvt_kernel(
    const float* __restrict__ in, unsigned short* __restrict__ out, int n8)
{
    int i = blockIdx.x * 256 + threadIdx.x;
    if (i >= n8) return;
    float4 f0 = ((const float4*)in)[i * 2], f1 = ((const float4*)in)[i * 2 + 1];
    alignas(16) unsigned short t[8] = {f2b(f0.x), f2b(f0.y), f2b(f0.z), f2b(f0.w),
                                       f2b(f1.x), f2b(f1.y), f2b(f1.z), f2b(f1.w)};
    ((float4*)out)[i] = *(const float4*)t;
}

// ---------------------------------------------------------------------------
// 128x128 GEMM, depth-3 counted-vmcnt pipeline (T3+T4), bf16 operands only.
// C[m][n] = sum_k A[m][k] * B[n][k], both staged via global_load_lds(16B).
// 5 LDS buffers (80 KB -> 2 blocks/CU). Per iter: stage tile t+3, wait
// vmcnt(4*min(ahead,3)) (loads stay in flight across barriers), raw
// s_barrier, ds_read + 16 MFMA. Laggard-race check: stage target (t+3)%5
// vs oldest reader (t-1)%5 -> diff 4 mod 5, safe with one barrier/iter.
// T2 XOR-swizzle per rule #21: LDS dest linear (DMA), global SOURCE chunk
// pre-permuted, read chunk permuted with the same involution:
//   chunk' = chunk ^ (row&3) ^ ((row>>2)&1)   (row = LDS row, 64 B each)
// -> quarter-wave (16 lanes, fixed quad) banks go 8-way -> 2-way (free).
// Split-K: z = (b << zshift) | ks; block covers [ks*K, (ks+1)*K).
// ---------------------------------------------------------------------------
__global__ __launch_bounds__(256) void gemm128_kernel(
    const unsigned short* __restrict__ A, size_t sAb,
    const unsigned short* __restrict__ B, size_t sBb,
    void* __restrict__ Cv, int c_f32, int writeT, int ldc, size_t sCb,
    int ldk, int K, int zshift, int zmask, size_t sCsplit)
{
    __shared__ unsigned short As[5][128 * 32];
    __shared__ unsigned short Bs[5][128 * 32];

    const int tid  = threadIdx.x;
    const int wave = tid >> 6, lane = tid & 63;
    const int quad = lane >> 4, l16 = lane & 15;
    const int wm = wave >> 1, wn = wave & 1;
    const int m0 = blockIdx.x * 128, n0 = blockIdx.y * 128;
    const int z = blockIdx.z;
    const int b = z >> zshift, ks = z & zmask;
    const int kbase = ks * K;

    const unsigned short* Ab = A + (size_t)b * sAb;
    const unsigned short* Bb = B + (size_t)b * sBb;

    f32x4 acc[4][4];
#pragma unroll
    for (int i = 0; i < 4; i++)
#pragma unroll
        for (int j = 0; j < 4; j++) acc[i][j] = (f32x4){0.f, 0.f, 0.f, 0.f};

    // staging geometry (per-lane constants)
    const int ldr  = lane >> 2;                        // row within 16-row panel
    const int fr_w = (ldr & 3) ^ ((ldr >> 2) & 1);     // write-side swizzle
    const int gcol = ((lane & 3) ^ fr_w) * 8;          // global chunk (shorts)
    // read-side swizzle (row bits 0..3 == l16, since wm*64 + i*16 keep them)
    const int fr_r = (l16 & 3) ^ ((l16 >> 2) & 1);
    const int qsw  = (quad ^ fr_r) * 8;                // swizzled chunk (shorts)

    const int nt = K / 32;

    auto stage = [&](int t) {
        const int kk = kbase + t * 32;
        unsigned short* as = &As[t % 5][0];
        unsigned short* bs = &Bs[t % 5][0];
#pragma unroll
        for (int i = 0; i < 2; i++) {
            const int panel = wave * 2 + i;            // 16-row panel
            gl2lds16(&Ab[(size_t)(m0 + panel * 16 + ldr) * ldk + kk + gcol],
                     &as[panel * 512]);
            gl2lds16(&Bb[(size_t)(n0 + panel * 16 + ldr) * ldk + kk + gcol],
                     &bs[panel * 512]);
        }
    };

    stage(0);
    if (nt > 1) stage(1);
    if (nt > 2) stage(2);

    for (int t = 0; t < nt; ++t) {
        if (t + 3 < nt) stage(t + 3);
        const int ahead = nt - 1 - t;                  // tiles staged beyond t
        if (ahead >= 3)      asm volatile("s_waitcnt vmcnt(12)" ::: "memory");
        else if (ahead == 2) asm volatile("s_waitcnt vmcnt(8)"  ::: "memory");
        else if (ahead == 1) asm volatile("s_waitcnt vmcnt(4)"  ::: "memory");
        else                 asm volatile("s_waitcnt vmcnt(0)"  ::: "memory");
        __builtin_amdgcn_s_barrier();
        asm volatile("" ::: "memory");

        const unsigned short* as = &As[t % 5][0];
        const unsigned short* bs = &Bs[t % 5][0];
        bf16x8 af[4], bf[4];
#pragma unroll
        for (int i = 0; i < 4; i++) {
            af[i] = *(const bf16x8*)&as[(wm * 64 + i * 16 + l16) * 32 + qsw];
            bf[i] = *(const bf16x8*)&bs[(wn * 64 + i * 16 + l16) * 32 + qsw];
        }
#pragma unroll
        for (int mb = 0; mb < 4; mb++)
#pragma unroll
            for (int nb = 0; nb < 4; nb++)
                acc[mb][nb] = __builtin_amdgcn_mfma_f32_16x16x32_bf16(
                    af[mb], bf[nb], acc[mb][nb], 0, 0, 0);
    }

    const size_t offC = (size_t)b * sCb + (size_t)ks * sCsplit;
#pragma unroll
    for (int mb = 0; mb < 4; mb++)
#pragma unroll
        for (int nb = 0; nb < 4; nb++)
#pragma unroll
            for (int r = 0; r < 4; r++) {
                int row = m0 + wm * 64 + mb * 16 + quad * 4 + r;
                int col = n0 + wn * 64 + nb * 16 + l16;
                size_t idx = offC + (writeT ? (size_t)col * ldc + row
                                            : (size_t)row * ldc + col);
                if (c_f32) ((float*)Cv)[idx] = acc[mb][nb][r];
                else ((unsigned short*)Cv)[idx] = f2b(acc[mb][nb][r]);
            }
}

// ---------------------------------------------------------------------------
// Sum 4 fp32 split-K partials (each 2,097,152 floats) -> bf16 out.
// 1024 blocks x 256 threads, 8 floats per thread. Layout: P[ks][...]
// ---------------------------------------------------------------------------
__global__ __launch_bounds__(256) void reduceG_kernel(
    const float* __restrict__ P, unsigned short* __restrict__ G)
{
    const int i = blockIdx.x * 256 + threadIdx.x;   // 8 floats each
    const float4* p = (const float4*)P + (size_t)i * 2;
    const size_t st = 2097152 / 4;                  // float4 stride per split
    float4 a0 = p[0], a1 = p[1];
#pragma unroll
    for (int s = 1; s < 4; s++) {
        float4 b0 = p[(size_t)s * st], b1 = p[(size_t)s * st + 1];
        a0.x += b0.x; a0.y += b0.y; a0.z += b0.z; a0.w += b0.w;
        a1.x += b1.x; a1.y += b1.y; a1.z += b1.z; a1.w += b1.w;
    }
    alignas(16) unsigned short t[8] = {f2b(a0.x), f2b(a0.y), f2b(a0.z), f2b(a0.w),
                                       f2b(a1.x), f2b(a1.y), f2b(a1.z), f2b(a1.w)};
    ((float4*)G)[i] = *(const float4*)t;
}

// ---------------------------------------------------------------------------
// 64x64 dtype-flex GEMM (round-3, verified) for small shapes.
// ---------------------------------------------------------------------------
__global__ __launch_bounds__(256) void gemm64_kernel(
    const void* __restrict__ Av, int a_f32, size_t sAb, size_t sAh,
    const unsigned short* __restrict__ B, size_t sBb, size_t sBh,
    void* __restrict__ Cv, int c_f32, int writeT, int ldc, size_t sCb, size_t sCh,
    int K, int hshift, int hmask)
{
    __shared__ unsigned short As[64][40];
    __shared__ unsigned short Bs[64][40];

    const int tid  = threadIdx.x;
    const int wave = tid >> 6, lane = tid & 63;
    const int quad = lane >> 4, l16 = lane & 15;
    const int m0 = blockIdx.x * 64, n0 = blockIdx.y * 64;
    const int bz = blockIdx.z;
    const int b = bz >> hshift, h = bz & hmask;

    f32x4 acc[4];
#pragma unroll
    for (int i = 0; i < 4; i++) acc[i] = (f32x4){0.f, 0.f, 0.f, 0.f};

    const int ldrow = tid >> 2, ldseg = (tid & 3) * 8;
    const size_t offA = (size_t)b * sAb + (size_t)h * sAh;
    const size_t offB = (size_t)b * sBb + (size_t)h * sBh;

    for (int k0 = 0; k0 < K; k0 += 32) {
        __syncthreads();
        if (a_f32) {
            const float* p = (const float*)Av + offA + (size_t)(m0 + ldrow) * K + k0 + ldseg;
            float4 lo = *(const float4*)p, hi = *(const float4*)(p + 4);
            alignas(16) unsigned short t8[8] = {
                f2b(lo.x), f2b(lo.y), f2b(lo.z), f2b(lo.w),
                f2b(hi.x), f2b(hi.y), f2b(hi.z), f2b(hi.w)};
            *(float4*)&As[ldrow][ldseg] = *(const float4*)t8;
        } else {
            const unsigned short* p = (const unsigned short*)Av + offA +
                                      (size_t)(m0 + ldrow) * K + k0 + ldseg;
            *(float4*)&As[ldrow][ldseg] = *(const float4*)p;
        }
        {
            const unsigned short* p = B + offB + (size_t)(n0 + ldrow) * K + k0 + ldseg;
            *(float4*)&Bs[ldrow][ldseg] = *(const float4*)p;
        }
        __syncthreads();

        bf16x8 a = *(const bf16x8*)&As[wave * 16 + l16][quad * 8];
#pragma unroll
        for (int nb = 0; nb < 4; nb++) {
            bf16x8 bb = *(const bf16x8*)&Bs[nb * 16 + l16][quad * 8];
            acc[nb] = __builtin_amdgcn_mfma_f32_16x16x32_bf16(a, bb, acc[nb], 0, 0, 0);
        }
    }

    const size_t offC = (size_t)b * sCb + (size_t)h * sCh;
#pragma unroll
    for (int nb = 0; nb < 4; nb++)
#pragma unroll
        for (int r = 0; r < 4; r++) {
            int row = m0 + wave * 16 + quad * 4 + r;
            int col = n0 + nb * 16 + l16;
            size_t idx = offC + (writeT ? (size_t)col * ldc + row
                                        : (size_t)row * ldc + col);
            if (c_f32) ((float*)Cv)[idx] = acc[nb][r];
            else ((unsigned short*)Cv)[idx] = f2b(acc[nb][r]);
        }
}

// ---------------------------------------------------------------------------
// WvT[h][t][e] = bf16(Wv[h][e][t])
// ---------------------------------------------------------------------------
__global__ __launch_bounds__(256) void transpose_wv_kernel(
    const float* __restrict__ Wv, unsigned short* __restrict__ WvT)
{
    int i = blockIdx.x * 256 + threadIdx.x;
    int h = i >> 15, r = i & 32767;
    int t = r >> 6, e = i & 63;
    WvT[i] = f2b(Wv[(size_t)h * 32768 + (size_t)e * 512 + t]);
}

// ---------------------------------------------------------------------------
__global__ __launch_bounds__(64) void softmax_kernel(
    const float* __restrict__ S, unsigned short* __restrict__ w)
{
    const int bh = blockIdx.x;
    const int d  = threadIdx.x;
    const float* s = S + (size_t)bh * (HD * HD) + d * HD;
    float v[64];
    float m = -1e30f;
#pragma unroll
    for (int e = 0; e < 64; e++) { v[e] = s[e] * INV_SCALE; m = fmaxf(m, v[e]); }
    float sum = 0.f;
#pragma unroll
    for (int e = 0; e < 64; e++) { v[e] = __expf(v[e] - m); sum += v[e]; }
    float rinv = 1.0f / sum;
    unsigned short* o = w + (size_t)bh * (HD * HD) + d * HD;
#pragma unroll
    for (int e = 0; e < 64; e++) o[e] = f2b(v[e] * rinv);
}

// ---------------------------------------------------------------------------
extern "C" void kernel_launch(void* const* d_in, const int* in_sizes, int n_in,
                              void* d_out, int out_size, void* d_ws, size_t ws_size,
                              hipStream_t stream)
{
    const float* q  = (const float*)d_in[0];
    const float* k  = (const float*)d_in[1];
    const float* v  = (const float*)d_in[2];
    const float* Wq = (const float*)d_in[3];
    const float* Wk = (const float*)d_in[4];
    const float* Wv = (const float*)d_in[5];
    const float* Wo = (const float*)d_in[6];

    // workspace (element counts). Aliasing plan (single stream => sequential):
    //   P1 (step-1 partials, 33.5MB fp32) at tmpT.. beyond-end (proven r1/r2)
    //   vB (bf16 v, 33.5MB)   aliases qT   (qT dead after step-1 gemm)
    //   P2/P5 (33.5MB fp32)   alias  kT    (kT dead after step-1 gemm)
    unsigned short* qT   = (unsigned short*)d_ws;        // 16,777,216
    unsigned short* kT   = qT + 16777216;                // 16,777,216
    unsigned short* G    = kT + 16777216;                // 2,097,152
    unsigned short* tmpT = G + 2097152;                  // 2,097,152
    unsigned short* WkB  = tmpT + 2097152;               // 262,144
    unsigned short* WoB  = WkB + 262144;                 // 262,144
    unsigned short* WvT  = WoB + 262144;                 // 262,144
    unsigned short* w    = WvT + 262144;                 // 262,144
    unsigned short* WveT = w + 262144;                   // 2,097,152
    unsigned short* W2   = WveT + 2097152;               // 2,097,152
    float*          S    = (float*)(W2 + 2097152);       // 262,144 fp32
    float*          P1   = (float*)tmpT;                 // 8,388,608 fp32
    unsigned short* vB   = qT;                           // bf16 v (after step 1)
    float*          PK   = (float*)kT;                   // P2/P5 partials

    // 0. q,k -> qT,kT (bf16, [b][t][c])
    transpose_qk_kernel<<<dim3(64, 8, 16), 256, 0, stream>>>(q, k, qT, kT);

    // 1. G[b][t][s] = sum_c qT[b][t][c] kT[b][s][c]   (K=4096, split-K x4)
    gemm128_kernel<<<dim3(4, 4, BS * 4), 256, 0, stream>>>(
        qT, 2097152, kT, 2097152,
        P1, 1, 0, 512, 262144, 4096, 1024, 2, 3, 2097152);

    // 1b. v -> bf16 (qT region now dead; step 6 uses the DMA path)
    cvt_kernel<<<8192, 256, 0, stream>>>(v, vB, 2097152);

    reduceG_kernel<<<1024, 256, 0, stream>>>(P1, G);

    // 0b. weight converts (their buffers alias P1's region; P1 dead now)
    cvt_kernel<<<128, 256, 0, stream>>>(Wk, WkB, 32768);
    cvt_kernel<<<128, 256, 0, stream>>>(Wo, WoB, 32768);
    transpose_wv_kernel<<<1024, 256, 0, stream>>>(Wv, WvT);

    // 2a. tmpT[b][he][t] = (G[b] * WkB^T)^T  (M=512, N=512, K=512, split-K x4)
    gemm128_kernel<<<dim3(4, 4, BS * 4), 256, 0, stream>>>(
        G, 262144, WkB, 0,
        PK, 1, 1, 512, 262144, 512, 128, 2, 3, 2097152);
    reduceG_kernel<<<1024, 256, 0, stream>>>(PK, tmpT);

    // 2b. S[b,h][d][e] = Wq[h] * tmpT[b,h]^T  (M=64, N=64, K=512)
    gemm64_kernel<<<dim3(1, 1, 64), 256, 0, stream>>>(
        Wq, 1, 0, 32768, tmpT, 262144, 32768,
        S, 1, 0, 64, 32768, 4096, 512, 3, 7);

    // 3. softmax
    softmax_kernel<<<64, 64, 0, stream>>>(S, w);

    // 4. WveT[b][t][h*64+d] = (w[b,h] * WvT[h]^T)^T   (M=64, N=512, K=64)
    gemm64_kernel<<<dim3(1, 8, 64), 256, 0, stream>>>(
        w, 0, 32768, 4096, WvT, 0, 32768,
        WveT, 0, 1, 512, 262144, 64, 64, 3, 7);

    // 5. W2[b][o][t] = WoB * WveT[b]^T   (M=512, N=512, K=512, split-K x4)
    gemm128_kernel<<<dim3(4, 4, BS * 4), 256, 0, stream>>>(
        WoB, 0, WveT, 262144,
        PK, 1, 0, 512, 262144, 512, 128, 2, 3, 2097152);
    reduceG_kernel<<<1024, 256, 0, stream>>>(PK, W2);

    // 6. out[b][c][o] = vB[b] * W2[b]^T   (M=4096, N=512, K=512, all bf16)
    gemm128_kernel<<<dim3(32, 4, BS), 256, 0, stream>>>(
        vB, 2097152, W2, 262144,
        d_out, 1, 0, 512, 2097152, 512, 512, 0, 0, 0);
}

// Round 5
// 367.022 us; speedup vs baseline: 1.0492x; 1.0492x over previous
//
#include <hip/hip_runtime.h>

// Problem constants (all fp32 in global memory — verified round 2)
#define BS    8
#define CDIM  4096
#define TDIM  512
#define NH    8
#define HD    64
#define NDIM  512
#define INV_SCALE 0.044194173824159216f   // 1/sqrt(512)

typedef __bf16 bf16x8 __attribute__((ext_vector_type(8)));
typedef float  f32x4  __attribute__((ext_vector_type(4)));

static __device__ __forceinline__ unsigned short f2b(float f) {
    union { float f; unsigned int i; } x; x.f = f;
    unsigned int r = x.i + 0x7FFFu + ((x.i >> 16) & 1u);   // RNE
    return (unsigned short)(r >> 16);
}

static __device__ __forceinline__ void gl2lds16(const unsigned short* g,
                                                unsigned short* l) {
    __builtin_amdgcn_global_load_lds(
        (const __attribute__((address_space(1))) void*)g,
        (__attribute__((address_space(3))) void*)l, 16, 0, 0);
}

// ---------------------------------------------------------------------------
// Transpose+convert: x[b][c][t] fp32 -> xT[b][t][c] bf16.  64x64 tiles.
// Round 4: pack adjacent c-pairs into u32 -> 8x ds_write_b32 + 8x ds_read_b32
// per thread (was 16+16 scalar b16). Stride-33 u32 rows: both phases are
// exactly 2 lanes/bank (free; m136).
//   write: addr = (t_local)*33 + cpair ; bank = (t_local + cpair) mod 32
//   read : addr = (t_local)*33 + cseg+j; bank = (t_local + cseg+j) mod 32
// ---------------------------------------------------------------------------
__global__ __launch_bounds__(256) void transpose_qk_kernel(
    const float* __restrict__ q, const float* __restrict__ k,
    unsigned short* __restrict__ qT, unsigned short* __restrict__ kT)
{
    __shared__ unsigned int Ls[64 * 33];

    const int z = blockIdx.z;
    const int b = z & 7;
    const float* src = (z >> 3) ? k : q;
    unsigned short* dst = (z >> 3) ? kT : qT;

    const int c0 = blockIdx.x * 64;
    const int t0 = blockIdx.y * 64;
    const int tid = threadIdx.x;

    // load: c-pair cp = tid>>3 (rows 2cp, 2cp+1), 8 floats at t-seg (tid&7)*8
    {
        const int cp = tid >> 3, seg = (tid & 7) * 8;
        const float* p0 = src + ((size_t)b * CDIM + c0 + 2 * cp) * TDIM + t0 + seg;
        const float* p1 = p0 + TDIM;
        float4 a0 = *(const float4*)p0, a1 = *(const float4*)(p0 + 4);
        float4 b0 = *(const float4*)p1, b1 = *(const float4*)(p1 + 4);
        float r0[8] = {a0.x, a0.y, a0.z, a0.w, a1.x, a1.y, a1.z, a1.w};
        float r1[8] = {b0.x, b0.y, b0.z, b0.w, b1.x, b1.y, b1.z, b1.w};
#pragma unroll
        for (int j = 0; j < 8; j++)
            Ls[(seg + j) * 33 + cp] =
                (unsigned int)f2b(r0[j]) | ((unsigned int)f2b(r1[j]) << 16);
    }
    __syncthreads();
    // store: t-row tp = tid>>2, 8 u32 (=16 c) at c-seg (tid&3)*8 (u32 units)
    {
        const int tp = tid >> 2, cs = (tid & 3) * 8;   // cs in u32 units
        alignas(16) unsigned int u[8];
#pragma unroll
        for (int j = 0; j < 8; j++) u[j] = Ls[tp * 33 + cs + j];
        unsigned short* o = dst + ((size_t)b * TDIM + t0 + tp) * CDIM + c0 + cs * 2;
        *(uint4*)o       = *(const uint4*)&u[0];
        *(uint4*)(o + 8) = *(const uint4*)&u[4];
    }
}

// ---------------------------------------------------------------------------
// Elementwise fp32 -> bf16 (n8 = n/8; one thread = 8 elems)
// ---------------------------------------------------------------------------
__global__ __launch_bounds__(256) void cvt_kernel(
    const float* __restrict__ in, unsigned short* __restrict__ out, int n8)
{
    int i = blockIdx.x * 256 + threadIdx.x;
    if (i >= n8) return;
    float4 f0 = ((const float4*)in)[i * 2], f1 = ((const float4*)in)[i * 2 + 1];
    alignas(16) unsigned short t[8] = {f2b(f0.x), f2b(f0.y), f2b(f0.z), f2b(f0.w),
                                       f2b(f1.x), f2b(f1.y), f2b(f1.z), f2b(f1.w)};
    ((float4*)out)[i] = *(const float4*)t;
}

// ---------------------------------------------------------------------------
// 128x128 GEMM, depth-3 counted-vmcnt pipeline (T3+T4), bf16 operands only.
// (verified round 3; unchanged)
// ---------------------------------------------------------------------------
__global__ __launch_bounds__(256) void gemm128_kernel(
    const unsigned short* __restrict__ A, size_t sAb,
    const unsigned short* __restrict__ B, size_t sBb,
    void* __restrict__ Cv, int c_f32, int writeT, int ldc, size_t sCb,
    int ldk, int K, int zshift, int zmask, size_t sCsplit)
{
    __shared__ unsigned short As[5][128 * 32];
    __shared__ unsigned short Bs[5][128 * 32];

    const int tid  = threadIdx.x;
    const int wave = tid >> 6, lane = tid & 63;
    const int quad = lane >> 4, l16 = lane & 15;
    const int wm = wave >> 1, wn = wave & 1;
    const int m0 = blockIdx.x * 128, n0 = blockIdx.y * 128;
    const int z = blockIdx.z;
    const int b = z >> zshift, ks = z & zmask;
    const int kbase = ks * K;

    const unsigned short* Ab = A + (size_t)b * sAb;
    const unsigned short* Bb = B + (size_t)b * sBb;

    f32x4 acc[4][4];
#pragma unroll
    for (int i = 0; i < 4; i++)
#pragma unroll
        for (int j = 0; j < 4; j++) acc[i][j] = (f32x4){0.f, 0.f, 0.f, 0.f};

    // staging geometry (per-lane constants)
    const int ldr  = lane >> 2;                        // row within 16-row panel
    const int fr_w = (ldr & 3) ^ ((ldr >> 2) & 1);     // write-side swizzle
    const int gcol = ((lane & 3) ^ fr_w) * 8;          // global chunk (shorts)
    const int fr_r = (l16 & 3) ^ ((l16 >> 2) & 1);
    const int qsw  = (quad ^ fr_r) * 8;                // swizzled chunk (shorts)

    const int nt = K / 32;

    auto stage = [&](int t) {
        const int kk = kbase + t * 32;
        unsigned short* as = &As[t % 5][0];
        unsigned short* bs = &Bs[t % 5][0];
#pragma unroll
        for (int i = 0; i < 2; i++) {
            const int panel = wave * 2 + i;            // 16-row panel
            gl2lds16(&Ab[(size_t)(m0 + panel * 16 + ldr) * ldk + kk + gcol],
                     &as[panel * 512]);
            gl2lds16(&Bb[(size_t)(n0 + panel * 16 + ldr) * ldk + kk + gcol],
                     &bs[panel * 512]);
        }
    };

    stage(0);
    if (nt > 1) stage(1);
    if (nt > 2) stage(2);

    for (int t = 0; t < nt; ++t) {
        if (t + 3 < nt) stage(t + 3);
        const int ahead = nt - 1 - t;                  // tiles staged beyond t
        if (ahead >= 3)      asm volatile("s_waitcnt vmcnt(12)" ::: "memory");
        else if (ahead == 2) asm volatile("s_waitcnt vmcnt(8)"  ::: "memory");
        else if (ahead == 1) asm volatile("s_waitcnt vmcnt(4)"  ::: "memory");
        else                 asm volatile("s_waitcnt vmcnt(0)"  ::: "memory");
        __builtin_amdgcn_s_barrier();
        asm volatile("" ::: "memory");

        const unsigned short* as = &As[t % 5][0];
        const unsigned short* bs = &Bs[t % 5][0];
        bf16x8 af[4], bf[4];
#pragma unroll
        for (int i = 0; i < 4; i++) {
            af[i] = *(const bf16x8*)&as[(wm * 64 + i * 16 + l16) * 32 + qsw];
            bf[i] = *(const bf16x8*)&bs[(wn * 64 + i * 16 + l16) * 32 + qsw];
        }
#pragma unroll
        for (int mb = 0; mb < 4; mb++)
#pragma unroll
            for (int nb = 0; nb < 4; nb++)
                acc[mb][nb] = __builtin_amdgcn_mfma_f32_16x16x32_bf16(
                    af[mb], bf[nb], acc[mb][nb], 0, 0, 0);
    }

    const size_t offC = (size_t)b * sCb + (size_t)ks * sCsplit;
#pragma unroll
    for (int mb = 0; mb < 4; mb++)
#pragma unroll
        for (int nb = 0; nb < 4; nb++)
#pragma unroll
            for (int r = 0; r < 4; r++) {
                int row = m0 + wm * 64 + mb * 16 + quad * 4 + r;
                int col = n0 + wn * 64 + nb * 16 + l16;
                size_t idx = offC + (writeT ? (size_t)col * ldc + row
                                            : (size_t)row * ldc + col);
                if (c_f32) ((float*)Cv)[idx] = acc[mb][nb][r];
                else ((unsigned short*)Cv)[idx] = f2b(acc[mb][nb][r]);
            }
}

// ---------------------------------------------------------------------------
// Sum 4 fp32 split-K partials (each 2,097,152 floats) -> bf16 out.
// ---------------------------------------------------------------------------
__global__ __launch_bounds__(256) void reduceG_kernel(
    const float* __restrict__ P, unsigned short* __restrict__ G)
{
    const int i = blockIdx.x * 256 + threadIdx.x;   // 8 floats each
    const float4* p = (const float4*)P + (size_t)i * 2;
    const size_t st = 2097152 / 4;                  // float4 stride per split
    float4 a0 = p[0], a1 = p[1];
#pragma unroll
    for (int s = 1; s < 4; s++) {
        float4 b0 = p[(size_t)s * st], b1 = p[(size_t)s * st + 1];
        a0.x += b0.x; a0.y += b0.y; a0.z += b0.z; a0.w += b0.w;
        a1.x += b1.x; a1.y += b1.y; a1.z += b1.z; a1.w += b1.w;
    }
    alignas(16) unsigned short t[8] = {f2b(a0.x), f2b(a0.y), f2b(a0.z), f2b(a0.w),
                                       f2b(a1.x), f2b(a1.y), f2b(a1.z), f2b(a1.w)};
    ((float4*)G)[i] = *(const float4*)t;
}

// ---------------------------------------------------------------------------
// 64x64 dtype-flex GEMM (round-3, verified) for small shapes.
// Round 4: also used for steps 2a/5 with grid (8,8,8) = 512 blocks
// (2 blocks/CU latency hiding WITHOUT split-K partial traffic).
// ---------------------------------------------------------------------------
__global__ __launch_bounds__(256) void gemm64_kernel(
    const void* __restrict__ Av, int a_f32, size_t sAb, size_t sAh,
    const unsigned short* __restrict__ B, size_t sBb, size_t sBh,
    void* __restrict__ Cv, int c_f32, int writeT, int ldc, size_t sCb, size_t sCh,
    int K, int hshift, int hmask)
{
    __shared__ unsigned short As[64][40];
    __shared__ unsigned short Bs[64][40];

    const int tid  = threadIdx.x;
    const int wave = tid >> 6, lane = tid & 63;
    const int quad = lane >> 4, l16 = lane & 15;
    const int m0 = blockIdx.x * 64, n0 = blockIdx.y * 64;
    const int bz = blockIdx.z;
    const int b = bz >> hshift, h = bz & hmask;

    f32x4 acc[4];
#pragma unroll
    for (int i = 0; i < 4; i++) acc[i] = (f32x4){0.f, 0.f, 0.f, 0.f};

    const int ldrow = tid >> 2, ldseg = (tid & 3) * 8;
    const size_t offA = (size_t)b * sAb + (size_t)h * sAh;
    const size_t offB = (size_t)b * sBb + (size_t)h * sBh;

    for (int k0 = 0; k0 < K; k0 += 32) {
        __syncthreads();
        if (a_f32) {
            const float* p = (const float*)Av + offA + (size_t)(m0 + ldrow) * K + k0 + ldseg;
            float4 lo = *(const float4*)p, hi = *(const float4*)(p + 4);
            alignas(16) unsigned short t8[8] = {
                f2b(lo.x), f2b(lo.y), f2b(lo.z), f2b(lo.w),
                f2b(hi.x), f2b(hi.y), f2b(hi.z), f2b(hi.w)};
            *(float4*)&As[ldrow][ldseg] = *(const float4*)t8;
        } else {
            const unsigned short* p = (const unsigned short*)Av + offA +
                                      (size_t)(m0 + ldrow) * K + k0 + ldseg;
            *(float4*)&As[ldrow][ldseg] = *(const float4*)p;
        }
        {
            const unsigned short* p = B + offB + (size_t)(n0 + ldrow) * K + k0 + ldseg;
            *(float4*)&Bs[ldrow][ldseg] = *(const float4*)p;
        }
        __syncthreads();

        bf16x8 a = *(const bf16x8*)&As[wave * 16 + l16][quad * 8];
#pragma unroll
        for (int nb = 0; nb < 4; nb++) {
            bf16x8 bb = *(const bf16x8*)&Bs[nb * 16 + l16][quad * 8];
            acc[nb] = __builtin_amdgcn_mfma_f32_16x16x32_bf16(a, bb, acc[nb], 0, 0, 0);
        }
    }

    const size_t offC = (size_t)b * sCb + (size_t)h * sCh;
#pragma unroll
    for (int nb = 0; nb < 4; nb++)
#pragma unroll
        for (int r = 0; r < 4; r++) {
            int row = m0 + wave * 16 + quad * 4 + r;
            int col = n0 + nb * 16 + l16;
            size_t idx = offC + (writeT ? (size_t)col * ldc + row
                                        : (size_t)row * ldc + col);
            if (c_f32) ((float*)Cv)[idx] = acc[nb][r];
            else ((unsigned short*)Cv)[idx] = f2b(acc[nb][r]);
        }
}

// ---------------------------------------------------------------------------
// WvT[h][t][e] = bf16(Wv[h][e][t])
// ---------------------------------------------------------------------------
__global__ __launch_bounds__(256) void transpose_wv_kernel(
    const float* __restrict__ Wv, unsigned short* __restrict__ WvT)
{
    int i = blockIdx.x * 256 + threadIdx.x;
    int h = i >> 15, r = i & 32767;
    int t = r >> 6, e = i & 63;
    WvT[i] = f2b(Wv[(size_t)h * 32768 + (size_t)e * 512 + t]);
}

// ---------------------------------------------------------------------------
__global__ __launch_bounds__(64) void softmax_kernel(
    const float* __restrict__ S, unsigned short* __restrict__ w)
{
    const int bh = blockIdx.x;
    const int d  = threadIdx.x;
    const float* s = S + (size_t)bh * (HD * HD) + d * HD;
    float v[64];
    float m = -1e30f;
#pragma unroll
    for (int e = 0; e < 64; e++) { v[e] = s[e] * INV_SCALE; m = fmaxf(m, v[e]); }
    float sum = 0.f;
#pragma unroll
    for (int e = 0; e < 64; e++) { v[e] = __expf(v[e] - m); sum += v[e]; }
    float rinv = 1.0f / sum;
    unsigned short* o = w + (size_t)bh * (HD * HD) + d * HD;
#pragma unroll
    for (int e = 0; e < 64; e++) o[e] = f2b(v[e] * rinv);
}

// ---------------------------------------------------------------------------
extern "C" void kernel_launch(void* const* d_in, const int* in_sizes, int n_in,
                              void* d_out, int out_size, void* d_ws, size_t ws_size,
                              hipStream_t stream)
{
    const float* q  = (const float*)d_in[0];
    const float* k  = (const float*)d_in[1];
    const float* v  = (const float*)d_in[2];
    const float* Wq = (const float*)d_in[3];
    const float* Wk = (const float*)d_in[4];
    const float* Wv = (const float*)d_in[5];
    const float* Wo = (const float*)d_in[6];

    // workspace (element counts). Aliasing plan (single stream => sequential):
    //   P1 (step-1 partials, 33.5MB fp32) at tmpT.. (proven passing r1-r3)
    //   vB (bf16 v, 33.5MB) aliases qT (qT dead after step-1 gemm)
    unsigned short* qT   = (unsigned short*)d_ws;        // 16,777,216
    unsigned short* kT   = qT + 16777216;                // 16,777,216
    unsigned short* G    = kT + 16777216;                // 2,097,152
    unsigned short* tmpT = G + 2097152;                  // 2,097,152
    unsigned short* WkB  = tmpT + 2097152;               // 262,144
    unsigned short* WoB  = WkB + 262144;                 // 262,144
    unsigned short* WvT  = WoB + 262144;                 // 262,144
    unsigned short* w    = WvT + 262144;                 // 262,144
    unsigned short* WveT = w + 262144;                   // 2,097,152
    unsigned short* W2   = WveT + 2097152;               // 2,097,152
    float*          S    = (float*)(W2 + 2097152);       // 262,144 fp32
    float*          P1   = (float*)tmpT;                 // 8,388,608 fp32
    unsigned short* vB   = qT;                           // bf16 v (after step 1)

    // 0. q,k -> qT,kT (bf16, [b][t][c])
    transpose_qk_kernel<<<dim3(64, 8, 16), 256, 0, stream>>>(q, k, qT, kT);

    // 1. G[b][t][s] = sum_c qT[b][t][c] kT[b][s][c]   (K=4096, split-K x4)
    gemm128_kernel<<<dim3(4, 4, BS * 4), 256, 0, stream>>>(
        qT, 2097152, kT, 2097152,
        P1, 1, 0, 512, 262144, 4096, 1024, 2, 3, 2097152);

    // 1b. v -> bf16 (qT region now dead; step 6 uses the DMA path)
    cvt_kernel<<<8192, 256, 0, stream>>>(v, vB, 2097152);

    reduceG_kernel<<<1024, 256, 0, stream>>>(P1, G);

    // 0b. weight converts (their buffers alias P1's region; P1 dead now)
    cvt_kernel<<<128, 256, 0, stream>>>(Wk, WkB, 32768);
    cvt_kernel<<<128, 256, 0, stream>>>(Wo, WoB, 32768);
    transpose_wv_kernel<<<1024, 256, 0, stream>>>(Wv, WvT);

    // 2a. tmpT[b][he][t] = (G[b] * WkB^T)^T  (M=512, N=512, K=512)
    //     512 blocks (2/CU), no split-K partial traffic.
    gemm64_kernel<<<dim3(8, 8, 8), 256, 0, stream>>>(
        G, 0, 262144, 0, WkB, 0, 0,
        tmpT, 0, 1, 512, 262144, 0, 512, 0, 0);

    // 2b. S[b,h][d][e] = Wq[h] * tmpT[b,h]^T  (M=64, N=64, K=512)
    gemm64_kernel<<<dim3(1, 1, 64), 256, 0, stream>>>(
        Wq, 1, 0, 32768, tmpT, 262144, 32768,
        S, 1, 0, 64, 32768, 4096, 512, 3, 7);

    // 3. softmax
    softmax_kernel<<<64, 64, 0, stream>>>(S, w);

    // 4. WveT[b][t][h*64+d] = (w[b,h] * WvT[h]^T)^T   (M=64, N=512, K=64)
    gemm64_kernel<<<dim3(1, 8, 64), 256, 0, stream>>>(
        w, 0, 32768, 4096, WvT, 0, 32768,
        WveT, 0, 1, 512, 262144, 64, 64, 3, 7);

    // 5. W2[b][o][t] = WoB * WveT[b]^T   (M=512, N=512, K=512)
    //     512 blocks (2/CU), no split-K partial traffic.
    gemm64_kernel<<<dim3(8, 8, 8), 256, 0, stream>>>(
        WoB, 0, 0, 0, WveT, 262144, 0,
        W2, 0, 0, 512, 262144, 0, 512, 0, 0);

    // 6. out[b][c][o] = vB[b] * W2[b]^T   (M=4096, N=512, K=512, all bf16)
    gemm128_kernel<<<dim3(32, 4, BS), 256, 0, stream>>>(
        vB, 2097152, W2, 262144,
        d_out, 1, 0, 512, 2097152, 512, 512, 0, 0, 0);
}

// Round 6
// 354.213 us; speedup vs baseline: 1.0871x; 1.0362x over previous
//
#include <hip/hip_runtime.h>

// Problem constants (all fp32 in global memory — verified round 2)
#define BS    8
#define CDIM  4096
#define TDIM  512
#define NH    8
#define HD    64
#define NDIM  512
#define INV_SCALE 0.044194173824159216f   // 1/sqrt(512)

typedef __bf16 bf16x8 __attribute__((ext_vector_type(8)));
typedef float  f32x4  __attribute__((ext_vector_type(4)));

static __device__ __forceinline__ unsigned short f2b(float f) {
    union { float f; unsigned int i; } x; x.f = f;
    unsigned int r = x.i + 0x7FFFu + ((x.i >> 16) & 1u);   // RNE
    return (unsigned short)(r >> 16);
}

static __device__ __forceinline__ void gl2lds16(const unsigned short* g,
                                                unsigned short* l) {
    __builtin_amdgcn_global_load_lds(
        (const __attribute__((address_space(1))) void*)g,
        (__attribute__((address_space(3))) void*)l, 16, 0, 0);
}

// Raw barrier: LDS-writes visible, but vmcnt NOT drained (keeps reg-prefetch
// loads in flight across the barrier — __syncthreads would drain vmcnt(0)).
#define LDS_BARRIER() do {                                           \
    asm volatile("s_waitcnt lgkmcnt(0)" ::: "memory");               \
    __builtin_amdgcn_s_barrier();                                    \
    asm volatile("" ::: "memory");                                   \
} while (0)

// ---------------------------------------------------------------------------
// Elementwise fp32 -> bf16 (n8 = n/8; one thread = 8 elems)
// ---------------------------------------------------------------------------
__global__ __launch_bounds__(256) void cvt_kernel(
    const float* __restrict__ in, unsigned short* __restrict__ out, int n8)
{
    int i = blockIdx.x * 256 + threadIdx.x;
    if (i >= n8) return;
    float4 f0 = ((const float4*)in)[i * 2], f1 = ((const float4*)in)[i * 2 + 1];
    alignas(16) unsigned short t[8] = {f2b(f0.x), f2b(f0.y), f2b(f0.z), f2b(f0.w),
                                       f2b(f1.x), f2b(f1.y), f2b(f1.z), f2b(f1.w)};
    ((float4*)out)[i] = *(const float4*)t;
}

// ---------------------------------------------------------------------------
// Round 6: TN-mode 128x128 GEMM fused transpose+convert (step 1 only).
// P[b,ks][t][s] += sum_{c in ks-slice} q[b][c][t] * k[b][c][s]  (fp32 in,
// fp32 partials out, split-K x4, BK=32 c-rows).
//
// Staging: thread (cp=tid>>4, ts=(tid&15)*8) loads rows c=2cp,2cp+1 at
// cols ts..ts+7 (coalesced fp32), packs c-pairs into u32 (bf16 lo=c even,
// hi=c odd), ds_write_b32 transposed into As/Bs[m][16 u32] with chunk-XOR
//   chunk' = (col>>2) ^ ((m>>3)&3)        (4-way write, ~2-way read)
// preserving 16B-aligned ds_read_b128 fragments (same MFMA layout as the
// verified gemm128). Depth-2 reg prefetch (named sets, rule #20) + raw
// LDS_BARRIER (1/tile) so global latency hides under a full tile phase.
// ---------------------------------------------------------------------------
__global__ __launch_bounds__(256) void gemmTN128_kernel(
    const float* __restrict__ Q, const float* __restrict__ Kf,
    float* __restrict__ P)
{
    __shared__ unsigned int As[2][128 * 16];
    __shared__ unsigned int Bs[2][128 * 16];

    const int tid  = threadIdx.x;
    const int wave = tid >> 6, lane = tid & 63;
    const int quad = lane >> 4, l16 = lane & 15;
    const int wm = wave >> 1, wn = wave & 1;
    const int m0 = blockIdx.x * 128, n0 = blockIdx.y * 128;
    const int z = blockIdx.z;
    const int b = z >> 2, ks = z & 3;
    const int kbase = ks * 1024;

    const float* Qb = Q + (size_t)b * (CDIM * TDIM);
    const float* Kb = Kf + (size_t)b * (CDIM * TDIM);

    const int cp = tid >> 4;          // 0..15: c-pair (rows 2cp, 2cp+1)
    const int ts = (tid & 15) * 8;    // t-offset within 128-tile

    f32x4 acc[4][4];
#pragma unroll
    for (int i = 0; i < 4; i++)
#pragma unroll
        for (int j = 0; j < 4; j++) acc[i][j] = (f32x4){0.f, 0.f, 0.f, 0.f};

    float4 qA0, qA1, qA2, qA3, kA0, kA1, kA2, kA3;   // reg set A
    float4 qB0, qB1, qB2, qB3, kB0, kB1, kB2, kB3;   // reg set B

#define ISSUE(TK, QR, KR) do {                                           \
    const int c0_ = kbase + (TK) * 32 + 2 * cp;                          \
    const float* q_ = Qb + (size_t)c0_ * TDIM + m0 + ts;                 \
    const float* k_ = Kb + (size_t)c0_ * TDIM + n0 + ts;                 \
    QR##0 = *(const float4*)q_;           QR##1 = *(const float4*)(q_ + 4); \
    QR##2 = *(const float4*)(q_ + TDIM);  QR##3 = *(const float4*)(q_ + TDIM + 4); \
    KR##0 = *(const float4*)k_;           KR##1 = *(const float4*)(k_ + 4); \
    KR##2 = *(const float4*)(k_ + TDIM);  KR##3 = *(const float4*)(k_ + TDIM + 4); \
} while (0)

#define STORE8(DST, X0, X1, X2, X3) do {                                 \
    const float lo_[8] = {X0.x, X0.y, X0.z, X0.w, X1.x, X1.y, X1.z, X1.w}; \
    const float hi_[8] = {X2.x, X2.y, X2.z, X2.w, X3.x, X3.y, X3.z, X3.w}; \
    _Pragma("unroll")                                                    \
    for (int j_ = 0; j_ < 8; j_++) {                                     \
        const int m_ = ts + j_;                                          \
        const int ch_ = ((cp >> 2) ^ (m_ >> 3)) & 3;                     \
        (DST)[m_ * 16 + ch_ * 4 + (cp & 3)] =                            \
            (unsigned int)f2b(lo_[j_]) |                                 \
            ((unsigned int)f2b(hi_[j_]) << 16);                          \
    }                                                                    \
} while (0)

#define COMPUTE(BUF) do {                                                \
    bf16x8 af[4], bf[4];                                                 \
    _Pragma("unroll")                                                    \
    for (int i_ = 0; i_ < 4; i_++) {                                     \
        const int ma_ = wm * 64 + i_ * 16 + l16;                         \
        const int ca_ = (quad ^ (ma_ >> 3)) & 3;                         \
        af[i_] = *(const bf16x8*)&As[BUF][ma_ * 16 + ca_ * 4];           \
        const int mb_ = wn * 64 + i_ * 16 + l16;                         \
        const int cb_ = (quad ^ (mb_ >> 3)) & 3;                         \
        bf[i_] = *(const bf16x8*)&Bs[BUF][mb_ * 16 + cb_ * 4];           \
    }                                                                    \
    _Pragma("unroll")                                                    \
    for (int mb2 = 0; mb2 < 4; mb2++)                                    \
        _Pragma("unroll")                                                \
        for (int nb2 = 0; nb2 < 4; nb2++)                                \
            acc[mb2][nb2] = __builtin_amdgcn_mfma_f32_16x16x32_bf16(     \
                af[mb2], bf[nb2], acc[mb2][nb2], 0, 0, 0);               \
} while (0)

    const int nt = 32;   // K=1024 per split, BK=32

    // prologue: tile0 -> setA -> LDS[0]; tile1 -> setB (in flight)
    ISSUE(0, qA, kA);
    ISSUE(1, qB, kB);
    STORE8(As[0], qA0, qA1, qA2, qA3);   // compiler waits setA's vmcnt only
    STORE8(Bs[0], kA0, kA1, kA2, kA3);
    LDS_BARRIER();

    for (int t = 0; t < nt; t += 2) {
        // sub-iter A: compute tile t (LDS[0]); stage tile t+1 -> LDS[1]
        if (t + 2 < nt) ISSUE(t + 2, qA, kA);
        COMPUTE(0);
        STORE8(As[1], qB0, qB1, qB2, qB3);
        STORE8(Bs[1], kB0, kB1, kB2, kB3);
        LDS_BARRIER();
        // sub-iter B: compute tile t+1 (LDS[1]); stage tile t+2 -> LDS[0]
        if (t + 3 < nt) ISSUE(t + 3, qB, kB);
        COMPUTE(1);
        if (t + 2 < nt) {
            STORE8(As[0], qA0, qA1, qA2, qA3);
            STORE8(Bs[0], kA0, kA1, kA2, kA3);
        }
        LDS_BARRIER();
    }

#undef ISSUE
#undef STORE8
#undef COMPUTE

    float* Pb = P + (size_t)ks * 2097152 + (size_t)b * 262144;
#pragma unroll
    for (int mb = 0; mb < 4; mb++)
#pragma unroll
        for (int nb = 0; nb < 4; nb++)
#pragma unroll
            for (int r = 0; r < 4; r++) {
                int row = m0 + wm * 64 + mb * 16 + quad * 4 + r;
                int col = n0 + wn * 64 + nb * 16 + l16;
                Pb[(size_t)row * 512 + col] = acc[mb][nb][r];
            }
}

// ---------------------------------------------------------------------------
// 128x128 GEMM, depth-3 counted-vmcnt pipeline (T3+T4), bf16 operands only.
// (verified round 3; unchanged — used for step 6)
// ---------------------------------------------------------------------------
__global__ __launch_bounds__(256) void gemm128_kernel(
    const unsigned short* __restrict__ A, size_t sAb,
    const unsigned short* __restrict__ B, size_t sBb,
    void* __restrict__ Cv, int c_f32, int writeT, int ldc, size_t sCb,
    int ldk, int K, int zshift, int zmask, size_t sCsplit)
{
    __shared__ unsigned short As[5][128 * 32];
    __shared__ unsigned short Bs[5][128 * 32];

    const int tid  = threadIdx.x;
    const int wave = tid >> 6, lane = tid & 63;
    const int quad = lane >> 4, l16 = lane & 15;
    const int wm = wave >> 1, wn = wave & 1;
    const int m0 = blockIdx.x * 128, n0 = blockIdx.y * 128;
    const int z = blockIdx.z;
    const int b = z >> zshift, ks = z & zmask;
    const int kbase = ks * K;

    const unsigned short* Ab = A + (size_t)b * sAb;
    const unsigned short* Bb = B + (size_t)b * sBb;

    f32x4 acc[4][4];
#pragma unroll
    for (int i = 0; i < 4; i++)
#pragma unroll
        for (int j = 0; j < 4; j++) acc[i][j] = (f32x4){0.f, 0.f, 0.f, 0.f};

    // staging geometry (per-lane constants)
    const int ldr  = lane >> 2;                        // row within 16-row panel
    const int fr_w = (ldr & 3) ^ ((ldr >> 2) & 1);     // write-side swizzle
    const int gcol = ((lane & 3) ^ fr_w) * 8;          // global chunk (shorts)
    const int fr_r = (l16 & 3) ^ ((l16 >> 2) & 1);
    const int qsw  = (quad ^ fr_r) * 8;                // swizzled chunk (shorts)

    const int nt = K / 32;

    auto stage = [&](int t) {
        const int kk = kbase + t * 32;
        unsigned short* as = &As[t % 5][0];
        unsigned short* bs = &Bs[t % 5][0];
#pragma unroll
        for (int i = 0; i < 2; i++) {
            const int panel = wave * 2 + i;            // 16-row panel
            gl2lds16(&Ab[(size_t)(m0 + panel * 16 + ldr) * ldk + kk + gcol],
                     &as[panel * 512]);
            gl2lds16(&Bb[(size_t)(n0 + panel * 16 + ldr) * ldk + kk + gcol],
                     &bs[panel * 512]);
        }
    };

    stage(0);
    if (nt > 1) stage(1);
    if (nt > 2) stage(2);

    for (int t = 0; t < nt; ++t) {
        if (t + 3 < nt) stage(t + 3);
        const int ahead = nt - 1 - t;                  // tiles staged beyond t
        if (ahead >= 3)      asm volatile("s_waitcnt vmcnt(12)" ::: "memory");
        else if (ahead == 2) asm volatile("s_waitcnt vmcnt(8)"  ::: "memory");
        else if (ahead == 1) asm volatile("s_waitcnt vmcnt(4)"  ::: "memory");
        else                 asm volatile("s_waitcnt vmcnt(0)"  ::: "memory");
        __builtin_amdgcn_s_barrier();
        asm volatile("" ::: "memory");

        const unsigned short* as = &As[t % 5][0];
        const unsigned short* bs = &Bs[t % 5][0];
        bf16x8 af[4], bf[4];
#pragma unroll
        for (int i = 0; i < 4; i++) {
            af[i] = *(const bf16x8*)&as[(wm * 64 + i * 16 + l16) * 32 + qsw];
            bf[i] = *(const bf16x8*)&bs[(wn * 64 + i * 16 + l16) * 32 + qsw];
        }
#pragma unroll
        for (int mb = 0; mb < 4; mb++)
#pragma unroll
            for (int nb = 0; nb < 4; nb++)
                acc[mb][nb] = __builtin_amdgcn_mfma_f32_16x16x32_bf16(
                    af[mb], bf[nb], acc[mb][nb], 0, 0, 0);
    }

    const size_t offC = (size_t)b * sCb + (size_t)ks * sCsplit;
#pragma unroll
    for (int mb = 0; mb < 4; mb++)
#pragma unroll
        for (int nb = 0; nb < 4; nb++)
#pragma unroll
            for (int r = 0; r < 4; r++) {
                int row = m0 + wm * 64 + mb * 16 + quad * 4 + r;
                int col = n0 + wn * 64 + nb * 16 + l16;
                size_t idx = offC + (writeT ? (size_t)col * ldc + row
                                            : (size_t)row * ldc + col);
                if (c_f32) ((float*)Cv)[idx] = acc[mb][nb][r];
                else ((unsigned short*)Cv)[idx] = f2b(acc[mb][nb][r]);
            }
}

// ---------------------------------------------------------------------------
// Sum 4 fp32 split-K partials (each 2,097,152 floats) -> bf16 out.
// ---------------------------------------------------------------------------
__global__ __launch_bounds__(256) void reduceG_kernel(
    const float* __restrict__ P, unsigned short* __restrict__ G)
{
    const int i = blockIdx.x * 256 + threadIdx.x;   // 8 floats each
    const float4* p = (const float4*)P + (size_t)i * 2;
    const size_t st = 2097152 / 4;                  // float4 stride per split
    float4 a0 = p[0], a1 = p[1];
#pragma unroll
    for (int s = 1; s < 4; s++) {
        float4 b0 = p[(size_t)s * st], b1 = p[(size_t)s * st + 1];
        a0.x += b0.x; a0.y += b0.y; a0.z += b0.z; a0.w += b0.w;
        a1.x += b1.x; a1.y += b1.y; a1.z += b1.z; a1.w += b1.w;
    }
    alignas(16) unsigned short t[8] = {f2b(a0.x), f2b(a0.y), f2b(a0.z), f2b(a0.w),
                                       f2b(a1.x), f2b(a1.y), f2b(a1.z), f2b(a1.w)};
    ((float4*)G)[i] = *(const float4*)t;
}

// ---------------------------------------------------------------------------
// 64x64 dtype-flex GEMM (round-3, verified) for small shapes.
// ---------------------------------------------------------------------------
__global__ __launch_bounds__(256) void gemm64_kernel(
    const void* __restrict__ Av, int a_f32, size_t sAb, size_t sAh,
    const unsigned short* __restrict__ B, size_t sBb, size_t sBh,
    void* __restrict__ Cv, int c_f32, int writeT, int ldc, size_t sCb, size_t sCh,
    int K, int hshift, int hmask)
{
    __shared__ unsigned short As[64][40];
    __shared__ unsigned short Bs[64][40];

    const int tid  = threadIdx.x;
    const int wave = tid >> 6, lane = tid & 63;
    const int quad = lane >> 4, l16 = lane & 15;
    const int m0 = blockIdx.x * 64, n0 = blockIdx.y * 64;
    const int bz = blockIdx.z;
    const int b = bz >> hshift, h = bz & hmask;

    f32x4 acc[4];
#pragma unroll
    for (int i = 0; i < 4; i++) acc[i] = (f32x4){0.f, 0.f, 0.f, 0.f};

    const int ldrow = tid >> 2, ldseg = (tid & 3) * 8;
    const size_t offA = (size_t)b * sAb + (size_t)h * sAh;
    const size_t offB = (size_t)b * sBb + (size_t)h * sBh;

    for (int k0 = 0; k0 < K; k0 += 32) {
        __syncthreads();
        if (a_f32) {
            const float* p = (const float*)Av + offA + (size_t)(m0 + ldrow) * K + k0 + ldseg;
            float4 lo = *(const float4*)p, hi = *(const float4*)(p + 4);
            alignas(16) unsigned short t8[8] = {
                f2b(lo.x), f2b(lo.y), f2b(lo.z), f2b(lo.w),
                f2b(hi.x), f2b(hi.y), f2b(hi.z), f2b(hi.w)};
            *(float4*)&As[ldrow][ldseg] = *(const float4*)t8;
        } else {
            const unsigned short* p = (const unsigned short*)Av + offA +
                                      (size_t)(m0 + ldrow) * K + k0 + ldseg;
            *(float4*)&As[ldrow][ldseg] = *(const float4*)p;
        }
        {
            const unsigned short* p = B + offB + (size_t)(n0 + ldrow) * K + k0 + ldseg;
            *(float4*)&Bs[ldrow][ldseg] = *(const float4*)p;
        }
        __syncthreads();

        bf16x8 a = *(const bf16x8*)&As[wave * 16 + l16][quad * 8];
#pragma unroll
        for (int nb = 0; nb < 4; nb++) {
            bf16x8 bb = *(const bf16x8*)&Bs[nb * 16 + l16][quad * 8];
            acc[nb] = __builtin_amdgcn_mfma_f32_16x16x32_bf16(a, bb, acc[nb], 0, 0, 0);
        }
    }

    const size_t offC = (size_t)b * sCb + (size_t)h * sCh;
#pragma unroll
    for (int nb = 0; nb < 4; nb++)
#pragma unroll
        for (int r = 0; r < 4; r++) {
            int row = m0 + wave * 16 + quad * 4 + r;
            int col = n0 + nb * 16 + l16;
            size_t idx = offC + (writeT ? (size_t)col * ldc + row
                                        : (size_t)row * ldc + col);
            if (c_f32) ((float*)Cv)[idx] = acc[nb][r];
            else ((unsigned short*)Cv)[idx] = f2b(acc[nb][r]);
        }
}

// ---------------------------------------------------------------------------
// WvT[h][t][e] = bf16(Wv[h][e][t])
// ---------------------------------------------------------------------------
__global__ __launch_bounds__(256) void transpose_wv_kernel(
    const float* __restrict__ Wv, unsigned short* __restrict__ WvT)
{
    int i = blockIdx.x * 256 + threadIdx.x;
    int h = i >> 15, r = i & 32767;
    int t = r >> 6, e = i & 63;
    WvT[i] = f2b(Wv[(size_t)h * 32768 + (size_t)e * 512 + t]);
}

// ---------------------------------------------------------------------------
__global__ __launch_bounds__(64) void softmax_kernel(
    const float* __restrict__ S, unsigned short* __restrict__ w)
{
    const int bh = blockIdx.x;
    const int d  = threadIdx.x;
    const float* s = S + (size_t)bh * (HD * HD) + d * HD;
    float v[64];
    float m = -1e30f;
#pragma unroll
    for (int e = 0; e < 64; e++) { v[e] = s[e] * INV_SCALE; m = fmaxf(m, v[e]); }
    float sum = 0.f;
#pragma unroll
    for (int e = 0; e < 64; e++) { v[e] = __expf(v[e] - m); sum += v[e]; }
    float rinv = 1.0f / sum;
    unsigned short* o = w + (size_t)bh * (HD * HD) + d * HD;
#pragma unroll
    for (int e = 0; e < 64; e++) o[e] = f2b(v[e] * rinv);
}

// ---------------------------------------------------------------------------
extern "C" void kernel_launch(void* const* d_in, const int* in_sizes, int n_in,
                              void* d_out, int out_size, void* d_ws, size_t ws_size,
                              hipStream_t stream)
{
    const float* q  = (const float*)d_in[0];
    const float* k  = (const float*)d_in[1];
    const float* v  = (const float*)d_in[2];
    const float* Wq = (const float*)d_in[3];
    const float* Wk = (const float*)d_in[4];
    const float* Wv = (const float*)d_in[5];
    const float* Wo = (const float*)d_in[6];

    // workspace (element counts). qT/kT regions are now free from the start
    // (step 1 reads q,k directly); vB reuses the qT slot, P1 at tmpT...
    unsigned short* qT   = (unsigned short*)d_ws;        // 16,777,216 (free)
    unsigned short* kT   = qT + 16777216;                // 16,777,216 (free)
    unsigned short* G    = kT + 16777216;                // 2,097,152
    unsigned short* tmpT = G + 2097152;                  // 2,097,152
    unsigned short* WkB  = tmpT + 2097152;               // 262,144
    unsigned short* WoB  = WkB + 262144;                 // 262,144
    unsigned short* WvT  = WoB + 262144;                 // 262,144
    unsigned short* w    = WvT + 262144;                 // 262,144
    unsigned short* WveT = w + 262144;                   // 2,097,152
    unsigned short* W2   = WveT + 2097152;               // 2,097,152
    float*          S    = (float*)(W2 + 2097152);       // 262,144 fp32
    float*          P1   = (float*)tmpT;                 // 8,388,608 fp32
    unsigned short* vB   = qT;                           // bf16 v

    // 1. fused transpose+convert+GEMM: P1[ks][b][t][s] partials (split-K x4)
    gemmTN128_kernel<<<dim3(4, 4, BS * 4), 256, 0, stream>>>(q, k, P1);

    // 1b. v -> bf16 (step 6 uses the DMA path)
    cvt_kernel<<<8192, 256, 0, stream>>>(v, vB, 2097152);

    reduceG_kernel<<<1024, 256, 0, stream>>>(P1, G);

    // 0b. weight converts (their buffers alias P1's region; P1 dead now)
    cvt_kernel<<<128, 256, 0, stream>>>(Wk, WkB, 32768);
    cvt_kernel<<<128, 256, 0, stream>>>(Wo, WoB, 32768);
    transpose_wv_kernel<<<1024, 256, 0, stream>>>(Wv, WvT);

    // 2a. tmpT[b][he][t] = (G[b] * WkB^T)^T  (M=512, N=512, K=512)
    gemm64_kernel<<<dim3(8, 8, 8), 256, 0, stream>>>(
        G, 0, 262144, 0, WkB, 0, 0,
        tmpT, 0, 1, 512, 262144, 0, 512, 0, 0);

    // 2b. S[b,h][d][e] = Wq[h] * tmpT[b,h]^T  (M=64, N=64, K=512)
    gemm64_kernel<<<dim3(1, 1, 64), 256, 0, stream>>>(
        Wq, 1, 0, 32768, tmpT, 262144, 32768,
        S, 1, 0, 64, 32768, 4096, 512, 3, 7);

    // 3. softmax
    softmax_kernel<<<64, 64, 0, stream>>>(S, w);

    // 4. WveT[b][t][h*64+d] = (w[b,h] * WvT[h]^T)^T   (M=64, N=512, K=64)
    gemm64_kernel<<<dim3(1, 8, 64), 256, 0, stream>>>(
        w, 0, 32768, 4096, WvT, 0, 32768,
        WveT, 0, 1, 512, 262144, 64, 64, 3, 7);

    // 5. W2[b][o][t] = WoB * WveT[b]^T   (M=512, N=512, K=512)
    gemm64_kernel<<<dim3(8, 8, 8), 256, 0, stream>>>(
        WoB, 0, 0, 0, WveT, 262144, 0,
        W2, 0, 0, 512, 262144, 0, 512, 0, 0);

    // 6. out[b][c][o] = vB[b] * W2[b]^T   (M=4096, N=512, K=512, all bf16)
    gemm128_kernel<<<dim3(32, 4, BS), 256, 0, stream>>>(
        vB, 2097152, W2, 262144,
        d_out, 1, 0, 512, 2097152, 512, 512, 0, 0, 0);
}